// Round 4
// baseline (1136.301 us; speedup 1.0000x reference)
//
#include <hip/hip_runtime.h>
#include <hip/hip_bf16.h>

#define NBATCH 16
#define NBR    8
#define CIN    3
#define HIN    224
#define WIN    224
#define COUT   64
#define OHH    112
#define OWW    112
#define PHH    56
#define PWW    56
#define CNT    (NBATCH*OHH*OWW)                  // 200704 per (b,co) channel
#define YSLOT  ((size_t)NBATCH*OHH*OWW*COUT)     // y elements per branch

// ---------- weight transpose, all branches: wT[b][k][co], k=(ci*7+kh)*7+kw ----------
__global__ __launch_bounds__(256)
void wtrans(const float* __restrict__ w, float* __restrict__ wT)
{
    int i = blockIdx.x*256 + threadIdx.x;
    if (i < NBR*147*64) {
        int co = i & 63;
        int t  = i >> 6;
        int k  = t % 147;
        int b  = t / 147;
        wT[i] = w[((size_t)b*COUT + co)*147 + k];
    }
}

// 14 output px; x window = 33 wave-uniform floats (scalar loads); 98 FMA/lane.
template<bool LO, bool HI>
__device__ __forceinline__ void chunk(const float* __restrict__ xr,
                                      const float wv[7], float* __restrict__ acc,
                                      int owb)
{
    float xu[33];
    #pragma unroll
    for (int j = 0; j < 33; ++j) {
        int iw = 2*owb - 3 + j;
        bool ok = true;
        int iwc = iw;
        if (LO) { ok = (iw >= 0);  iwc = (iw < 0) ? 0 : iw; }
        if (HI) { ok = (iw < WIN); iwc = (iw >= WIN) ? (WIN-1) : iw; }
        float v = xr[iwc];                 // clamped -> always in-bounds
        xu[j] = ok ? v : 0.f;
    }
    #pragma unroll
    for (int px = 0; px < 14; ++px)
        #pragma unroll
        for (int kw = 0; kw < 7; ++kw)
            acc[px] = fmaf(xu[2*px + kw], wv[kw], acc[px]);
}

// conv(7x7,s2,p3): lane = co; wave = 28-px quarter-row for all 64 co.
// waves per branch = 16n * 112oh * 4q = 7168; grid = nb*1792 blocks (4 waves).
// y layout per branch slot: [n][oh][ow][co] bf16.
__global__ __launch_bounds__(256, 8)
void conv_fast(const float* __restrict__ x, const float* __restrict__ wT,
               __hip_bfloat16* __restrict__ y, float* __restrict__ stats, int bbase)
{
    int wid  = __builtin_amdgcn_readfirstlane(threadIdx.x >> 6);
    int lane = threadIdx.x & 63;
    int wg   = blockIdx.x*4 + wid;
    int bloc = wg / 7168;
    int r    = wg % 7168;
    int n    = r / 448;
    int r2   = r % 448;
    int oh   = r2 >> 2;
    int q    = r2 & 3;
    int b    = bbase + bloc;

    const float* xb  = x  + ((size_t)(n*NBR + b))*CIN*HIN*WIN;
    const float* wTb = wT + (size_t)b*147*64;

    float acc[28];
    #pragma unroll
    for (int i = 0; i < 28; ++i) acc[i] = 0.f;

    #pragma unroll 1
    for (int ci = 0; ci < CIN; ++ci) {
        #pragma unroll 1
        for (int kh = 0; kh < 7; ++kh) {
            int ihr = 2*oh - 3 + kh;
            bool ok = (unsigned)ihr < (unsigned)HIN;
            int ih  = ok ? ihr : 0;

            float wv[7];
            #pragma unroll
            for (int kw = 0; kw < 7; ++kw)
                wv[kw] = wTb[((ci*7 + kh)*7 + kw)*64 + lane];
            if (!ok) {
                #pragma unroll
                for (int kw = 0; kw < 7; ++kw) wv[kw] = 0.f;
            }

            int rowoff = __builtin_amdgcn_readfirstlane((ci*HIN + ih)*WIN);
            const float* xr = xb + rowoff;

            if (q == 0) {
                chunk<true ,false>(xr, wv, acc,      0);
                chunk<false,false>(xr, wv, acc + 14, 14);
            } else if (q == 3) {
                chunk<false,false>(xr, wv, acc,      84);
                chunk<false,true >(xr, wv, acc + 14, 98);
            } else {
                int ob = q*28;
                chunk<false,false>(xr, wv, acc,      ob);
                chunk<false,false>(xr, wv, acc + 14, ob + 14);
            }
        }
    }

    __hip_bfloat16* yr = y + (size_t)bloc*YSLOT
                       + (((size_t)n*OHH + oh)*OWW + q*28)*64 + lane;
    float ssum = 0.f, ssq = 0.f;
    #pragma unroll
    for (int px = 0; px < 28; ++px) {
        float v = acc[px];
        ssum += v; ssq += v*v;
        yr[(size_t)px*64] = __float2bfloat16(v);
    }

    __shared__ float red[2][4][64];
    red[0][wid][lane] = ssum;
    red[1][wid][lane] = ssq;
    __syncthreads();
    if (wid == 0) {
        float s  = red[0][0][lane] + red[0][1][lane] + red[0][2][lane] + red[0][3][lane];
        float qq = red[1][0][lane] + red[1][1][lane] + red[1][2][lane] + red[1][3][lane];
        atomicAdd(&stats[b*128 + lane*2 + 0], s);
        atomicAdd(&stats[b*128 + lane*2 + 1], qq);
    }
}

// BN-affine + ReLU + maxpool3x3 s2 p1. Block = one (b,n,ph) output row.
// Read phase lane=co (coalesced y reads); LDS exchange; write phase emits
// contiguous 224B runs along pw into NCHW out.
__global__ __launch_bounds__(256)
void pool_fast(const __hip_bfloat16* __restrict__ y, const float* __restrict__ stats,
               const float* __restrict__ gamma, const float* __restrict__ beta,
               float* __restrict__ out, int bbase)
{
    int bid  = blockIdx.x;
    int bloc = bid / (NBATCH*PHH);
    int r    = bid % (NBATCH*PHH);
    int n    = r / PHH;
    int ph   = r % PHH;
    int b    = bbase + bloc;
    int wid  = threadIdx.x >> 6;
    int lane = threadIdx.x & 63;   // co

    float mean = stats[b*128 + lane*2 + 0] * (1.f/CNT);
    float var  = stats[b*128 + lane*2 + 1] * (1.f/CNT) - mean*mean;
    float inv  = rsqrtf(var + 1e-5f);
    float scale = gamma[b*COUT + lane]*inv;
    float shift = beta[b*COUT + lane] - mean*scale;

    __shared__ float res[PWW*65];

    const __hip_bfloat16* yb = y + (size_t)bloc*YSLOT + (size_t)n*OHH*OWW*64;
    int h0 = 2*ph - 1;

    for (int t = 0; t < 14; ++t) {
        int pw = wid*14 + t;
        int w0 = 2*pw - 1;
        float mx = -1e30f, mn = 1e30f;
        #pragma unroll
        for (int dh = 0; dh < 3; ++dh) {
            int ih = h0 + dh;
            if ((unsigned)ih < (unsigned)OHH) {
                const __hip_bfloat16* row = yb + (size_t)ih*OWW*64;
                #pragma unroll
                for (int dw = 0; dw < 3; ++dw) {
                    int iw = w0 + dw;
                    if ((unsigned)iw < (unsigned)OWW) {
                        float v = __bfloat162float(row[(size_t)iw*64 + lane]);
                        mx = fmaxf(mx, v);
                        mn = fminf(mn, v);
                    }
                }
            }
        }
        float v = (scale >= 0.f) ? mx : mn;   // affine+relu monotone
        res[pw*65 + lane] = fmaxf(fmaf(v, scale, shift), 0.f);
    }
    __syncthreads();

    float* ob = out + (((size_t)n*NBR + b)*COUT)*(PHH*PWW) + (size_t)ph*PWW;
    for (int j = threadIdx.x; j < COUT*PWW; j += 256) {
        int co = j / PWW;
        int pw = j - co*PWW;
        ob[(size_t)co*(PHH*PWW) + pw] = res[pw*65 + co];
    }
}

// ================= fallback path (tiny workspace) =================
__global__ __launch_bounds__(512)
void conv_bn_stats(const float* __restrict__ x, const float* __restrict__ w,
                   float* __restrict__ stats, int b)
{
    __shared__ float xs[CIN][7][232];
    int bid = blockIdx.x;
    int oh  = bid % OHH;
    int n   = bid / OHH;
    const float* xb = x + ((size_t)(n*NBR + b))*CIN*HIN*WIN;
    int ihb = oh*2 - 3;
    for (int idx = threadIdx.x; idx < CIN*7*230; idx += 512) {
        int ci = idx / (7*230);
        int rr = idx - ci*(7*230);
        int kh = rr / 230;
        int c  = rr - kh*230;
        int ih = ihb + kh, iw = c - 3;
        float v = 0.f;
        if ((unsigned)ih < (unsigned)HIN && (unsigned)iw < (unsigned)WIN)
            v = xb[(ci*HIN + ih)*WIN + iw];
        xs[ci][kh][c] = v;
    }
    __syncthreads();
    int wid  = __builtin_amdgcn_readfirstlane(threadIdx.x >> 6);
    int lane = threadIdx.x & 63;
    int co0  = wid * 8;
    const float* wb = w + ((size_t)b*COUT + co0)*147;
    float acc0[8], acc1[8];
    #pragma unroll
    for (int cc = 0; cc < 8; ++cc) { acc0[cc] = 0.f; acc1[cc] = 0.f; }
    int ow1 = lane + 64;
    for (int ci = 0; ci < CIN; ++ci)
        for (int kh = 0; kh < 7; ++kh) {
            float wr[8][7];
            #pragma unroll
            for (int cc = 0; cc < 8; ++cc)
                #pragma unroll
                for (int kw = 0; kw < 7; ++kw)
                    wr[cc][kw] = wb[cc*147 + ci*49 + kh*7 + kw];
            const float* xr = &xs[ci][kh][0];
            #pragma unroll
            for (int kw = 0; kw < 7; ++kw) {
                float xv0 = xr[lane*2 + kw];
                float xv1 = (ow1 < OWW) ? xr[ow1*2 + kw] : 0.f;
                #pragma unroll
                for (int cc = 0; cc < 8; ++cc) {
                    acc0[cc] = fmaf(xv0, wr[cc][kw], acc0[cc]);
                    acc1[cc] = fmaf(xv1, wr[cc][kw], acc1[cc]);
                }
            }
        }
    #pragma unroll
    for (int cc = 0; cc < 8; ++cc) {
        float s = acc0[cc] + acc1[cc];
        float qv = acc0[cc]*acc0[cc] + acc1[cc]*acc1[cc];
        #pragma unroll
        for (int off = 32; off; off >>= 1) {
            s  += __shfl_xor(s, off);
            qv += __shfl_xor(qv, off);
        }
        if (lane == 0) {
            atomicAdd(&stats[(co0+cc)*2 + 0], s);
            atomicAdd(&stats[(co0+cc)*2 + 1], qv);
        }
    }
}

__global__ __launch_bounds__(256)
void pool_recompute(const float* __restrict__ x, const float* __restrict__ w,
                    const float* __restrict__ stats, const float* __restrict__ gamma,
                    const float* __restrict__ beta, float* __restrict__ out, int b)
{
    int idx = blockIdx.x*256 + threadIdx.x;
    int pw = idx % PWW;
    int t  = idx / PWW;
    int ph = t % PHH; t /= PHH;
    int co = t % COUT;
    int n  = t / COUT;
    float mean = stats[co*2 + 0] * (1.f/CNT);
    float var  = stats[co*2 + 1] * (1.f/CNT) - mean*mean;
    float inv  = rsqrtf(var + 1e-5f);
    float scale = gamma[co]*inv;
    float shift = beta[co] - mean*scale;
    const float* xb = x + ((size_t)(n*NBR + b))*CIN*HIN*WIN;
    const float* wb = w + ((size_t)b*COUT + co)*147;
    float mx = -1e30f, mn = 1e30f;
    for (int dh = 0; dh < 3; ++dh) {
        int oh = 2*ph - 1 + dh;
        if ((unsigned)oh >= (unsigned)OHH) continue;
        for (int dw = 0; dw < 3; ++dw) {
            int ow = 2*pw - 1 + dw;
            if ((unsigned)ow >= (unsigned)OWW) continue;
            float a = 0.f;
            for (int ci = 0; ci < CIN; ++ci)
                for (int kh = 0; kh < 7; ++kh) {
                    int ih = oh*2 - 3 + kh;
                    if ((unsigned)ih >= (unsigned)HIN) continue;
                    for (int kw = 0; kw < 7; ++kw) {
                        int iw = ow*2 - 3 + kw;
                        if ((unsigned)iw >= (unsigned)WIN) continue;
                        a = fmaf(xb[(ci*HIN + ih)*WIN + iw], wb[ci*49 + kh*7 + kw], a);
                    }
                }
            mx = fmaxf(mx, a);
            mn = fminf(mn, a);
        }
    }
    float v = (scale >= 0.f) ? mx : mn;
    out[(((size_t)n*NBR + b)*COUT + co)*(PHH*PWW) + (size_t)ph*PWW + pw] =
        fmaxf(fmaf(v, scale, shift), 0.f);
}

extern "C" void kernel_launch(void* const* d_in, const int* in_sizes, int n_in,
                              void* d_out, int out_size, void* d_ws, size_t ws_size,
                              hipStream_t stream) {
    const float* x     = (const float*)d_in[0];
    const float* w     = (const float*)d_in[1];
    const float* gamma = (const float*)d_in[2];
    const float* beta  = (const float*)d_in[3];
    float* out = (float*)d_out;

    // ws: [0,4K) stats (8 x 128 f32); [4K,~305K) wT (8 x 147 x 64 f32); [512K,..) y slots
    float* stats = (float*)d_ws;
    float* wT    = (float*)((char*)d_ws + 4096);
    const size_t yoff   = 512*1024;
    const size_t yBytes = YSLOT*sizeof(__hip_bfloat16);   // 25.69 MB per branch
    __hip_bfloat16* y = (__hip_bfloat16*)((char*)d_ws + yoff);

    int ng = 0;
    if (ws_size > yoff + yBytes)
        ng = (int)((ws_size - yoff) / yBytes);
    if (ng > NBR) ng = NBR;

    hipMemsetAsync(d_ws, 0, NBR*128*sizeof(float), stream);

    if (ng >= 1) {
        wtrans<<<(NBR*147*64 + 255)/256, 256, 0, stream>>>(w, wT);
        for (int g = 0; g < NBR; g += ng) {
            int nb = (NBR - g < ng) ? (NBR - g) : ng;
            conv_fast<<<nb*1792, 256, 0, stream>>>(x, wT, y, stats, g);
            pool_fast<<<nb*NBATCH*PHH, 256, 0, stream>>>(y, stats, gamma, beta, out, g);
        }
    } else {
        for (int b = 0; b < NBR; ++b) {
            float* statsB = stats + b*128;
            conv_bn_stats<<<NBATCH*OHH, 512, 0, stream>>>(x, w, statsB, b);
            pool_recompute<<<NBATCH*COUT*PHH*PWW/256, 256, 0, stream>>>(
                x, w, statsB, gamma + b*COUT, beta + b*COUT, out, b);
        }
    }
}

// Round 5
// 697.545 us; speedup vs baseline: 1.6290x; 1.6290x over previous
//
#include <hip/hip_runtime.h>
#include <hip/hip_bf16.h>

#define NBATCH 16
#define NBR    8
#define CIN    3
#define HIN    224
#define WIN    224
#define COUT   64
#define OHH    112
#define OWW    112
#define PHH    56
#define PWW    56
#define CNT    (NBATCH*OHH*OWW)                  // 200704 per (b,co) channel
#define YSLOT  ((size_t)NBATCH*OHH*OWW*COUT)     // y elements per branch

// ---------- weight transpose, all branches: wT[b][k][co], k=(ci*7+kh)*7+kw ----------
__global__ __launch_bounds__(256)
void wtrans(const float* __restrict__ w, float* __restrict__ wT)
{
    int i = blockIdx.x*256 + threadIdx.x;
    if (i < NBR*147*64) {
        int co = i & 63;
        int t  = i >> 6;
        int k  = t % 147;
        int b  = t / 147;
        wT[i] = w[((size_t)b*COUT + co)*147 + k];
    }
}

// 14 output px; x window = 33 wave-uniform floats (scalar loads); 98 FMA/lane.
template<bool CHK>
__device__ __forceinline__ void chunk(const float* __restrict__ xr,
                                      const float wv[7], float* __restrict__ acc,
                                      int owb)
{
    float xu[33];
    #pragma unroll
    for (int j = 0; j < 33; ++j) {
        int iw = 2*owb - 3 + j;
        if (CHK)
            xu[j] = ((unsigned)iw < (unsigned)WIN) ? xr[iw] : 0.f;
        else
            xu[j] = xr[iw];
    }
    #pragma unroll
    for (int px = 0; px < 14; ++px)
        #pragma unroll
        for (int kw = 0; kw < 7; ++kw)
            acc[px] = fmaf(xu[2*px + kw], wv[kw], acc[px]);
}

// conv(7x7,s2,p3): lane = co. Wave = one 56-px half-row for all 64 co.
// 3584 waves per branch; merged over nb branches: grid = nb*896 blocks (4 waves).
// y layout per branch slot: [n][oh][ow][co] bf16. NO launch_bounds cap (needs 64 VGPR).
__global__ __launch_bounds__(256)
void conv_fast(const float* __restrict__ x, const float* __restrict__ wT,
               __hip_bfloat16* __restrict__ y, float* __restrict__ stats, int bbase)
{
    int wid  = __builtin_amdgcn_readfirstlane(threadIdx.x >> 6);
    int lane = threadIdx.x & 63;
    int wg   = blockIdx.x*4 + wid;
    int bloc = wg / 3584;
    int r    = wg % 3584;
    int h    = r & 1;
    int oh   = (r >> 1) % OHH;
    int n    = (r >> 1) / OHH;
    int b    = bbase + bloc;

    const float* xb  = x  + ((size_t)(n*NBR + b))*CIN*HIN*WIN;
    const float* wTb = wT + (size_t)b*147*64;

    float acc[56];
    #pragma unroll
    for (int i = 0; i < 56; ++i) acc[i] = 0.f;

    #pragma unroll 1
    for (int ci = 0; ci < CIN; ++ci) {
        #pragma unroll 1
        for (int kh = 0; kh < 7; ++kh) {
            int ihr = 2*oh - 3 + kh;
            bool ok = (unsigned)ihr < (unsigned)HIN;
            int ih  = ok ? ihr : 0;

            float wv[7];
            #pragma unroll
            for (int kw = 0; kw < 7; ++kw)
                wv[kw] = wTb[((ci*7 + kh)*7 + kw)*64 + lane];
            if (!ok) {
                #pragma unroll
                for (int kw = 0; kw < 7; ++kw) wv[kw] = 0.f;
            }

            int rowoff = __builtin_amdgcn_readfirstlane((ci*HIN + ih)*WIN);
            const float* xr = xb + rowoff;

            if (h == 0) {
                chunk<true >(xr, wv, acc + 0,   0);
                chunk<false>(xr, wv, acc + 14, 14);
                chunk<false>(xr, wv, acc + 28, 28);
                chunk<false>(xr, wv, acc + 42, 42);
            } else {
                chunk<false>(xr, wv, acc + 0,  56);
                chunk<false>(xr, wv, acc + 14, 70);
                chunk<false>(xr, wv, acc + 28, 84);
                chunk<true >(xr, wv, acc + 42, 98);
            }
        }
    }

    __hip_bfloat16* yr = y + (size_t)bloc*YSLOT
                       + (((size_t)n*OHH + oh)*OWW + h*56)*64 + lane;
    float ssum = 0.f, ssq = 0.f;
    #pragma unroll
    for (int px = 0; px < 56; ++px) {
        float v = acc[px];
        ssum += v; ssq += v*v;
        yr[(size_t)px*64] = __float2bfloat16(v);
    }

    __shared__ float red[2][4][64];
    red[0][wid][lane] = ssum;
    red[1][wid][lane] = ssq;
    __syncthreads();
    if (wid == 0) {
        float s  = red[0][0][lane] + red[0][1][lane] + red[0][2][lane] + red[0][3][lane];
        float qq = red[1][0][lane] + red[1][1][lane] + red[1][2][lane] + red[1][3][lane];
        atomicAdd(&stats[b*128 + lane*2 + 0], s);
        atomicAdd(&stats[b*128 + lane*2 + 1], qq);
    }
}

// BN-affine + ReLU + maxpool3x3 s2 p1. Block = one (bloc,n,ph) output row.
// Read phase lane=co (coalesced y reads); LDS exchange; write phase emits
// contiguous 224B runs along pw into NCHW out.
__global__ __launch_bounds__(256)
void pool_fast(const __hip_bfloat16* __restrict__ y, const float* __restrict__ stats,
               const float* __restrict__ gamma, const float* __restrict__ beta,
               float* __restrict__ out, int bbase)
{
    int bid  = blockIdx.x;
    int bloc = bid / (NBATCH*PHH);
    int r    = bid % (NBATCH*PHH);
    int n    = r / PHH;
    int ph   = r % PHH;
    int b    = bbase + bloc;
    int wid  = threadIdx.x >> 6;
    int lane = threadIdx.x & 63;   // co

    float mean = stats[b*128 + lane*2 + 0] * (1.f/CNT);
    float var  = stats[b*128 + lane*2 + 1] * (1.f/CNT) - mean*mean;
    float inv  = rsqrtf(var + 1e-5f);
    float scale = gamma[b*COUT + lane]*inv;
    float shift = beta[b*COUT + lane] - mean*scale;

    __shared__ float res[PWW*65];

    const __hip_bfloat16* yb = y + (size_t)bloc*YSLOT + (size_t)n*OHH*OWW*64;
    int h0 = 2*ph - 1;

    for (int t = 0; t < 14; ++t) {
        int pw = wid*14 + t;
        int w0 = 2*pw - 1;
        float mx = -1e30f, mn = 1e30f;
        #pragma unroll
        for (int dh = 0; dh < 3; ++dh) {
            int ih = h0 + dh;
            if ((unsigned)ih < (unsigned)OHH) {
                const __hip_bfloat16* row = yb + (size_t)ih*OWW*64;
                #pragma unroll
                for (int dw = 0; dw < 3; ++dw) {
                    int iw = w0 + dw;
                    if ((unsigned)iw < (unsigned)OWW) {
                        float v = __bfloat162float(row[(size_t)iw*64 + lane]);
                        mx = fmaxf(mx, v);
                        mn = fminf(mn, v);
                    }
                }
            }
        }
        float v = (scale >= 0.f) ? mx : mn;   // affine+relu monotone
        res[pw*65 + lane] = fmaxf(fmaf(v, scale, shift), 0.f);
    }
    __syncthreads();

    float* ob = out + (((size_t)n*NBR + b)*COUT)*(PHH*PWW) + (size_t)ph*PWW;
    for (int j = threadIdx.x; j < COUT*PWW; j += 256) {
        int co = j / PWW;
        int pw = j - co*PWW;
        ob[(size_t)co*(PHH*PWW) + pw] = res[pw*65 + co];
    }
}

// ================= fallback path (tiny workspace) =================
__global__ __launch_bounds__(512)
void conv_bn_stats(const float* __restrict__ x, const float* __restrict__ w,
                   float* __restrict__ stats, int b)
{
    __shared__ float xs[CIN][7][232];
    int bid = blockIdx.x;
    int oh  = bid % OHH;
    int n   = bid / OHH;
    const float* xb = x + ((size_t)(n*NBR + b))*CIN*HIN*WIN;
    int ihb = oh*2 - 3;
    for (int idx = threadIdx.x; idx < CIN*7*230; idx += 512) {
        int ci = idx / (7*230);
        int rr = idx - ci*(7*230);
        int kh = rr / 230;
        int c  = rr - kh*230;
        int ih = ihb + kh, iw = c - 3;
        float v = 0.f;
        if ((unsigned)ih < (unsigned)HIN && (unsigned)iw < (unsigned)WIN)
            v = xb[(ci*HIN + ih)*WIN + iw];
        xs[ci][kh][c] = v;
    }
    __syncthreads();
    int wid  = __builtin_amdgcn_readfirstlane(threadIdx.x >> 6);
    int lane = threadIdx.x & 63;
    int co0  = wid * 8;
    const float* wb = w + ((size_t)b*COUT + co0)*147;
    float acc0[8], acc1[8];
    #pragma unroll
    for (int cc = 0; cc < 8; ++cc) { acc0[cc] = 0.f; acc1[cc] = 0.f; }
    int ow1 = lane + 64;
    for (int ci = 0; ci < CIN; ++ci)
        for (int kh = 0; kh < 7; ++kh) {
            float wr[8][7];
            #pragma unroll
            for (int cc = 0; cc < 8; ++cc)
                #pragma unroll
                for (int kw = 0; kw < 7; ++kw)
                    wr[cc][kw] = wb[cc*147 + ci*49 + kh*7 + kw];
            const float* xr = &xs[ci][kh][0];
            #pragma unroll
            for (int kw = 0; kw < 7; ++kw) {
                float xv0 = xr[lane*2 + kw];
                float xv1 = (ow1 < OWW) ? xr[ow1*2 + kw] : 0.f;
                #pragma unroll
                for (int cc = 0; cc < 8; ++cc) {
                    acc0[cc] = fmaf(xv0, wr[cc][kw], acc0[cc]);
                    acc1[cc] = fmaf(xv1, wr[cc][kw], acc1[cc]);
                }
            }
        }
    #pragma unroll
    for (int cc = 0; cc < 8; ++cc) {
        float s = acc0[cc] + acc1[cc];
        float qv = acc0[cc]*acc0[cc] + acc1[cc]*acc1[cc];
        #pragma unroll
        for (int off = 32; off; off >>= 1) {
            s  += __shfl_xor(s, off);
            qv += __shfl_xor(qv, off);
        }
        if (lane == 0) {
            atomicAdd(&stats[(co0+cc)*2 + 0], s);
            atomicAdd(&stats[(co0+cc)*2 + 1], qv);
        }
    }
}

__global__ __launch_bounds__(256)
void pool_recompute(const float* __restrict__ x, const float* __restrict__ w,
                    const float* __restrict__ stats, const float* __restrict__ gamma,
                    const float* __restrict__ beta, float* __restrict__ out, int b)
{
    int idx = blockIdx.x*256 + threadIdx.x;
    int pw = idx % PWW;
    int t  = idx / PWW;
    int ph = t % PHH; t /= PHH;
    int co = t % COUT;
    int n  = t / COUT;
    float mean = stats[co*2 + 0] * (1.f/CNT);
    float var  = stats[co*2 + 1] * (1.f/CNT) - mean*mean;
    float inv  = rsqrtf(var + 1e-5f);
    float scale = gamma[co]*inv;
    float shift = beta[co] - mean*scale;
    const float* xb = x + ((size_t)(n*NBR + b))*CIN*HIN*WIN;
    const float* wb = w + ((size_t)b*COUT + co)*147;
    float mx = -1e30f, mn = 1e30f;
    for (int dh = 0; dh < 3; ++dh) {
        int oh = 2*ph - 1 + dh;
        if ((unsigned)oh >= (unsigned)OHH) continue;
        for (int dw = 0; dw < 3; ++dw) {
            int ow = 2*pw - 1 + dw;
            if ((unsigned)ow >= (unsigned)OWW) continue;
            float a = 0.f;
            for (int ci = 0; ci < CIN; ++ci)
                for (int kh = 0; kh < 7; ++kh) {
                    int ih = oh*2 - 3 + kh;
                    if ((unsigned)ih >= (unsigned)HIN) continue;
                    for (int kw = 0; kw < 7; ++kw) {
                        int iw = ow*2 - 3 + kw;
                        if ((unsigned)iw >= (unsigned)WIN) continue;
                        a = fmaf(xb[(ci*HIN + ih)*WIN + iw], wb[ci*49 + kh*7 + kw], a);
                    }
                }
            mx = fmaxf(mx, a);
            mn = fminf(mn, a);
        }
    }
    float v = (scale >= 0.f) ? mx : mn;
    out[(((size_t)n*NBR + b)*COUT + co)*(PHH*PWW) + (size_t)ph*PWW + pw] =
        fmaxf(fmaf(v, scale, shift), 0.f);
}

extern "C" void kernel_launch(void* const* d_in, const int* in_sizes, int n_in,
                              void* d_out, int out_size, void* d_ws, size_t ws_size,
                              hipStream_t stream) {
    const float* x     = (const float*)d_in[0];
    const float* w     = (const float*)d_in[1];
    const float* gamma = (const float*)d_in[2];
    const float* beta  = (const float*)d_in[3];
    float* out = (float*)d_out;

    // ws: [0,4K) stats (8 x 128 f32); [4K,~305K) wT (8 x 147 x 64 f32); [512K,..) y slots
    float* stats = (float*)d_ws;
    float* wT    = (float*)((char*)d_ws + 4096);
    const size_t yoff   = 512*1024;
    const size_t yBytes = YSLOT*sizeof(__hip_bfloat16);   // 25.69 MB per branch
    __hip_bfloat16* y = (__hip_bfloat16*)((char*)d_ws + yoff);

    int ng = 0;
    if (ws_size > yoff + yBytes)
        ng = (int)((ws_size - yoff) / yBytes);
    if (ng > NBR) ng = NBR;

    hipMemsetAsync(d_ws, 0, NBR*128*sizeof(float), stream);

    if (ng >= 1) {
        wtrans<<<(NBR*147*64 + 255)/256, 256, 0, stream>>>(w, wT);
        for (int g = 0; g < NBR; g += ng) {
            int nb = (NBR - g < ng) ? (NBR - g) : ng;
            conv_fast<<<nb*896, 256, 0, stream>>>(x, wT, y, stats, g);
            pool_fast<<<nb*NBATCH*PHH, 256, 0, stream>>>(y, stats, gamma, beta, out, g);
        }
    } else {
        for (int b = 0; b < NBR; ++b) {
            float* statsB = stats + b*128;
            conv_bn_stats<<<NBATCH*OHH, 512, 0, stream>>>(x, w, statsB, b);
            pool_recompute<<<NBATCH*COUT*PHH*PWW/256, 256, 0, stream>>>(
                x, w, statsB, gamma + b*COUT, beta + b*COUT, out, b);
        }
    }
}

// Round 6
// 385.329 us; speedup vs baseline: 2.9489x; 1.8103x over previous
//
#include <hip/hip_runtime.h>
#include <hip/hip_bf16.h>

#define NBATCH 16
#define NBR    8
#define CIN    3
#define HIN    224
#define WIN    224
#define COUT   64
#define OHH    112
#define OWW    112
#define PHH    56
#define PWW    56
#define CNT    (NBATCH*OHH*OWW)                  // 200704 per (b,co) channel
#define YSLOT  ((size_t)NBATCH*OHH*OWW*COUT)     // y elements per branch

// padded x: per image [4 ci][230 h][232 w] bf16 (zeros baked in; ci=3 plane all-zero)
#define XCI  4
#define XH   230
#define XW   232
#define XIMG ((size_t)XCI*XH*XW)                 // 213440 elems per image
#define KP   192                                 // padded K (24 groups x 8)
#define BROW 200                                 // Bt row stride in ushorts (192 + 8 pad)

typedef __bf16 bf16x8 __attribute__((ext_vector_type(8)));
typedef float  f32x4  __attribute__((ext_vector_type(4)));
typedef unsigned int uint4v __attribute__((ext_vector_type(4)));

// ---------- Bt[b][co][k'] bf16: k' = g*8+j, g=(ci*7+kh), j=kw (j=7 or g>=21 -> 0) ----------
__global__ __launch_bounds__(256)
void prep_w(const float* __restrict__ w, ushort* __restrict__ wt)
{
    int i = blockIdx.x*256 + threadIdx.x;
    if (i >= NBR*COUT*BROW) return;
    int k = i % BROW;
    int t = i / BROW;                       // b*64 + co
    float v = 0.f;
    if (k < 168) {
        int g = k >> 3, j = k & 7;
        if (j < 7) {
            int ci = g / 7, kh = g - 7*ci;
            v = w[(size_t)t*147 + ci*49 + kh*7 + j];
        }
    }
    __hip_bfloat16 h = __float2bfloat16(v);
    wt[i] = *reinterpret_cast<ushort*>(&h);
}

// ---------- padded bf16 x. interior only (memset provides zeros elsewhere) ----------
// grid = 128 img * 3 ci * 14 hc
__global__ __launch_bounds__(256)
void prep_x(const float* __restrict__ x, ushort* __restrict__ xp)
{
    int bid = blockIdx.x;
    int hc  = bid % 14;
    int t2  = bid / 14;
    int ci  = t2 % 3;
    int img = t2 / 3;
    const float* src = x + ((size_t)img*3 + ci)*HIN*WIN;
    ushort* dst = xp + (size_t)img*XIMG + (size_t)ci*XH*XW;
    for (int i = threadIdx.x; i < 16*224; i += 256) {
        int hh = hc*16 + (i / 224);
        int c  = i % 224;
        float v = src[hh*WIN + c];
        __hip_bfloat16 h = __float2bfloat16(v);
        dst[(hh+3)*XW + (c+3)] = *reinterpret_cast<ushort*>(&h);
    }
}

// ---------- MFMA conv: block = 4 waves, 14 tiles of 64 px; wave = 16px x 64co ----------
// A-frag: lane holds rows l&15, k = 8*(l>>4)+j -> 8 consecutive bf16 in xp. direct load.
// B-frag: 24 uint4 in VGPRs, staged once via LDS. y: [n][oh][ow][co] bf16 (p-linear).
__global__ __launch_bounds__(256)
void conv_mfma(const ushort* __restrict__ xp, const ushort* __restrict__ wt,
               ushort* __restrict__ y, float* __restrict__ stats, int bbase)
{
    __shared__ ushort bt[COUT*BROW];     // 25600 B
    __shared__ float red[4][2][COUT];    // 2 KB

    int bloc = blockIdx.x / 224;
    int tb   = (blockIdx.x % 224) * 14;
    int b    = bbase + bloc;
    int tid  = threadIdx.x;
    int wid  = tid >> 6;
    int lane = tid & 63;
    int l15  = lane & 15;
    int q    = lane >> 4;

    {   // stage Bt into LDS (coalesced dword copy)
        const uint* s = (const uint*)(wt + (size_t)b*COUT*BROW);
        uint* d = (uint*)bt;
        for (int i = tid; i < COUT*BROW/2; i += 256) d[i] = s[i];
    }
    __syncthreads();

    // B frags to registers: B[k = ks*32 + q*8 + j][co = nt*16 + l15]
    uint4v bfr[4][6];
    #pragma unroll
    for (int nt = 0; nt < 4; ++nt)
        #pragma unroll
        for (int ks = 0; ks < 6; ++ks)
            bfr[nt][ks] = *(const uint4v*)&bt[(nt*16 + l15)*BROW + ks*32 + q*8];

    // per-lane K-group byte offsets: g = ks*4 + q -> (ci,kh)
    int goff[6];
    #pragma unroll
    for (int ks = 0; ks < 6; ++ks) {
        int g = ks*4 + q;
        int ci = g / 7, kh = g - 7*ci;
        goff[ks] = (ci*XH + kh) * (XW*2);
    }

    float ssum[4] = {0.f,0.f,0.f,0.f}, ssq[4] = {0.f,0.f,0.f,0.f};
    ushort* ybb = y + (size_t)bloc*YSLOT;

    for (int t = 0; t < 14; ++t) {
        int pxb = (tb + t)*64 + wid*16;
        int p   = pxb + l15;                  // this lane's A row
        int n   = p / (OHH*OWW);
        int r1  = p - n*(OHH*OWW);
        int oh  = r1 / OWW;
        int ow  = r1 - oh*OWW;
        int img = n*NBR + b;
        const char* abase = (const char*)xp + (size_t)img*(XIMG*2)
                          + (size_t)(2*oh)*(XW*2) + (size_t)(4*ow);

        uint4v afr[6];
        #pragma unroll
        for (int ks = 0; ks < 6; ++ks)
            __builtin_memcpy(&afr[ks], abase + goff[ks], 16);

        f32x4 acc[4];
        #pragma unroll
        for (int nt = 0; nt < 4; ++nt) acc[nt] = (f32x4){0.f,0.f,0.f,0.f};

        #pragma unroll
        for (int ks = 0; ks < 6; ++ks)
            #pragma unroll
            for (int nt = 0; nt < 4; ++nt)
                acc[nt] = __builtin_amdgcn_mfma_f32_16x16x32_bf16(
                    __builtin_bit_cast(bf16x8, afr[ks]),
                    __builtin_bit_cast(bf16x8, bfr[nt][ks]),
                    acc[nt], 0, 0, 0);

        // store y + accumulate stats (row = pxb + q*4 + r, col = nt*16 + l15)
        #pragma unroll
        for (int nt = 0; nt < 4; ++nt) {
            #pragma unroll
            for (int r = 0; r < 4; ++r) {
                float v = acc[nt][r];
                ssum[nt] += v; ssq[nt] += v*v;
                __hip_bfloat16 hv = __float2bfloat16(v);
                ybb[(size_t)(pxb + q*4 + r)*64 + nt*16 + l15] =
                    *reinterpret_cast<ushort*>(&hv);
            }
        }
    }

    // stats: reduce over q-quarters, then waves, then one atomic per co
    #pragma unroll
    for (int nt = 0; nt < 4; ++nt) {
        float s = ssum[nt], qq = ssq[nt];
        s  += __shfl_xor(s, 16);  s  += __shfl_xor(s, 32);
        qq += __shfl_xor(qq, 16); qq += __shfl_xor(qq, 32);
        ssum[nt] = s; ssq[nt] = qq;
    }
    if (q == 0) {
        #pragma unroll
        for (int nt = 0; nt < 4; ++nt) {
            red[wid][0][nt*16 + l15] = ssum[nt];
            red[wid][1][nt*16 + l15] = ssq[nt];
        }
    }
    __syncthreads();
    if (tid < 64) {
        float s  = red[0][0][tid] + red[1][0][tid] + red[2][0][tid] + red[3][0][tid];
        float qq = red[0][1][tid] + red[1][1][tid] + red[2][1][tid] + red[3][1][tid];
        atomicAdd(&stats[b*128 + tid*2 + 0], s);
        atomicAdd(&stats[b*128 + tid*2 + 1], qq);
    }
}

// ---------- BN-affine + ReLU + maxpool3x3 s2 p1 (unchanged from r5) ----------
__global__ __launch_bounds__(256)
void pool_fast(const __hip_bfloat16* __restrict__ y, const float* __restrict__ stats,
               const float* __restrict__ gamma, const float* __restrict__ beta,
               float* __restrict__ out, int bbase)
{
    int bid  = blockIdx.x;
    int bloc = bid / (NBATCH*PHH);
    int r    = bid % (NBATCH*PHH);
    int n    = r / PHH;
    int ph   = r % PHH;
    int b    = bbase + bloc;
    int wid  = threadIdx.x >> 6;
    int lane = threadIdx.x & 63;   // co

    float mean = stats[b*128 + lane*2 + 0] * (1.f/CNT);
    float var  = stats[b*128 + lane*2 + 1] * (1.f/CNT) - mean*mean;
    float inv  = rsqrtf(var + 1e-5f);
    float scale = gamma[b*COUT + lane]*inv;
    float shift = beta[b*COUT + lane] - mean*scale;

    __shared__ float res[PWW*65];

    const __hip_bfloat16* yb = y + (size_t)bloc*YSLOT + (size_t)n*OHH*OWW*64;
    int h0 = 2*ph - 1;

    for (int t = 0; t < 14; ++t) {
        int pw = wid*14 + t;
        int w0 = 2*pw - 1;
        float mx = -1e30f, mn = 1e30f;
        #pragma unroll
        for (int dh = 0; dh < 3; ++dh) {
            int ih = h0 + dh;
            if ((unsigned)ih < (unsigned)OHH) {
                const __hip_bfloat16* row = yb + (size_t)ih*OWW*64;
                #pragma unroll
                for (int dw = 0; dw < 3; ++dw) {
                    int iw = w0 + dw;
                    if ((unsigned)iw < (unsigned)OWW) {
                        float v = __bfloat162float(row[(size_t)iw*64 + lane]);
                        mx = fmaxf(mx, v);
                        mn = fminf(mn, v);
                    }
                }
            }
        }
        float v = (scale >= 0.f) ? mx : mn;   // affine+relu monotone
        res[pw*65 + lane] = fmaxf(fmaf(v, scale, shift), 0.f);
    }
    __syncthreads();

    float* ob = out + (((size_t)n*NBR + b)*COUT)*(PHH*PWW) + (size_t)ph*PWW;
    for (int j = threadIdx.x; j < COUT*PWW; j += 256) {
        int co = j / PWW;
        int pw = j - co*PWW;
        ob[(size_t)co*(PHH*PWW) + pw] = res[pw*65 + co];
    }
}

// ================= fallback path (tiny workspace) =================
__global__ __launch_bounds__(512)
void conv_bn_stats(const float* __restrict__ x, const float* __restrict__ w,
                   float* __restrict__ stats, int b)
{
    __shared__ float xs[CIN][7][232];
    int bid = blockIdx.x;
    int oh  = bid % OHH;
    int n   = bid / OHH;
    const float* xb = x + ((size_t)(n*NBR + b))*CIN*HIN*WIN;
    int ihb = oh*2 - 3;
    for (int idx = threadIdx.x; idx < CIN*7*230; idx += 512) {
        int ci = idx / (7*230);
        int rr = idx - ci*(7*230);
        int kh = rr / 230;
        int c  = rr - kh*230;
        int ih = ihb + kh, iw = c - 3;
        float v = 0.f;
        if ((unsigned)ih < (unsigned)HIN && (unsigned)iw < (unsigned)WIN)
            v = xb[(ci*HIN + ih)*WIN + iw];
        xs[ci][kh][c] = v;
    }
    __syncthreads();
    int wid  = __builtin_amdgcn_readfirstlane(threadIdx.x >> 6);
    int lane = threadIdx.x & 63;
    int co0  = wid * 8;
    const float* wb = w + ((size_t)b*COUT + co0)*147;
    float acc0[8], acc1[8];
    #pragma unroll
    for (int cc = 0; cc < 8; ++cc) { acc0[cc] = 0.f; acc1[cc] = 0.f; }
    int ow1 = lane + 64;
    for (int ci = 0; ci < CIN; ++ci)
        for (int kh = 0; kh < 7; ++kh) {
            float wr[8][7];
            #pragma unroll
            for (int cc = 0; cc < 8; ++cc)
                #pragma unroll
                for (int kw = 0; kw < 7; ++kw)
                    wr[cc][kw] = wb[cc*147 + ci*49 + kh*7 + kw];
            const float* xr = &xs[ci][kh][0];
            #pragma unroll
            for (int kw = 0; kw < 7; ++kw) {
                float xv0 = xr[lane*2 + kw];
                float xv1 = (ow1 < OWW) ? xr[ow1*2 + kw] : 0.f;
                #pragma unroll
                for (int cc = 0; cc < 8; ++cc) {
                    acc0[cc] = fmaf(xv0, wr[cc][kw], acc0[cc]);
                    acc1[cc] = fmaf(xv1, wr[cc][kw], acc1[cc]);
                }
            }
        }
    #pragma unroll
    for (int cc = 0; cc < 8; ++cc) {
        float s = acc0[cc] + acc1[cc];
        float qv = acc0[cc]*acc0[cc] + acc1[cc]*acc1[cc];
        #pragma unroll
        for (int off = 32; off; off >>= 1) {
            s  += __shfl_xor(s, off);
            qv += __shfl_xor(qv, off);
        }
        if (lane == 0) {
            atomicAdd(&stats[(co0+cc)*2 + 0], s);
            atomicAdd(&stats[(co0+cc)*2 + 1], qv);
        }
    }
}

__global__ __launch_bounds__(256)
void pool_recompute(const float* __restrict__ x, const float* __restrict__ w,
                    const float* __restrict__ stats, const float* __restrict__ gamma,
                    const float* __restrict__ beta, float* __restrict__ out, int b)
{
    int idx = blockIdx.x*256 + threadIdx.x;
    int pw = idx % PWW;
    int t  = idx / PWW;
    int ph = t % PHH; t /= PHH;
    int co = t % COUT;
    int n  = t / COUT;
    float mean = stats[co*2 + 0] * (1.f/CNT);
    float var  = stats[co*2 + 1] * (1.f/CNT) - mean*mean;
    float inv  = rsqrtf(var + 1e-5f);
    float scale = gamma[co]*inv;
    float shift = beta[co] - mean*scale;
    const float* xb = x + ((size_t)(n*NBR + b))*CIN*HIN*WIN;
    const float* wb = w + ((size_t)b*COUT + co)*147;
    float mx = -1e30f, mn = 1e30f;
    for (int dh = 0; dh < 3; ++dh) {
        int oh = 2*ph - 1 + dh;
        if ((unsigned)oh >= (unsigned)OHH) continue;
        for (int dw = 0; dw < 3; ++dw) {
            int ow = 2*pw - 1 + dw;
            if ((unsigned)ow >= (unsigned)OWW) continue;
            float a = 0.f;
            for (int ci = 0; ci < CIN; ++ci)
                for (int kh = 0; kh < 7; ++kh) {
                    int ih = oh*2 - 3 + kh;
                    if ((unsigned)ih >= (unsigned)HIN) continue;
                    for (int kw = 0; kw < 7; ++kw) {
                        int iw = ow*2 - 3 + kw;
                        if ((unsigned)iw >= (unsigned)WIN) continue;
                        a = fmaf(xb[(ci*HIN + ih)*WIN + iw], wb[ci*49 + kh*7 + kw], a);
                    }
                }
            mx = fmaxf(mx, a);
            mn = fminf(mn, a);
        }
    }
    float v = (scale >= 0.f) ? mx : mn;
    out[(((size_t)n*NBR + b)*COUT + co)*(PHH*PWW) + (size_t)ph*PWW + pw] =
        fmaxf(fmaf(v, scale, shift), 0.f);
}

extern "C" void kernel_launch(void* const* d_in, const int* in_sizes, int n_in,
                              void* d_out, int out_size, void* d_ws, size_t ws_size,
                              hipStream_t stream) {
    const float* x     = (const float*)d_in[0];
    const float* w     = (const float*)d_in[1];
    const float* gamma = (const float*)d_in[2];
    const float* beta  = (const float*)d_in[3];
    float* out = (float*)d_out;

    // ws: [0,4K) stats; [4K,~209K) wt (8x64x200 bf16); [256K, +54.6MB) xpad; then y slots
    float*  stats = (float*)d_ws;
    ushort* wt    = (ushort*)((char*)d_ws + 4096);
    ushort* xp    = (ushort*)((char*)d_ws + 262144);
    const size_t ybase  = 262144 + (size_t)128*XIMG*2;   // ~54.9 MB
    const size_t yBytes = YSLOT*2;                       // 25.69 MB per branch
    ushort* y = (ushort*)((char*)d_ws + ybase);

    int ng = 0;
    if (ws_size > ybase + yBytes)
        ng = (int)((ws_size - ybase) / yBytes);
    if (ng > NBR) ng = NBR;

    if (ng >= 1) {
        hipMemsetAsync(d_ws, 0, ybase, stream);   // zeros stats + wt pad + xpad padding
        prep_w<<<(NBR*COUT*BROW + 255)/256, 256, 0, stream>>>(w, wt);
        prep_x<<<128*3*14, 256, 0, stream>>>(x, xp);
        for (int g = 0; g < NBR; g += ng) {
            int nb = (NBR - g < ng) ? (NBR - g) : ng;
            conv_mfma<<<nb*224, 256, 0, stream>>>(xp, wt, y, stats, g);
            pool_fast<<<nb*NBATCH*PHH, 256, 0, stream>>>(
                (const __hip_bfloat16*)y, stats, gamma, beta, out, g);
        }
    } else {
        hipMemsetAsync(d_ws, 0, NBR*128*sizeof(float), stream);
        for (int b = 0; b < NBR; ++b) {
            float* statsB = stats + b*128;
            conv_bn_stats<<<NBATCH*OHH, 512, 0, stream>>>(x, w, statsB, b);
            pool_recompute<<<NBATCH*COUT*PHH*PWW/256, 256, 0, stream>>>(
                x, w, statsB, gamma + b*COUT, beta + b*COUT, out, b);
        }
    }
}

// Round 7
// 223.581 us; speedup vs baseline: 5.0823x; 1.7234x over previous
//
#include <hip/hip_runtime.h>
#include <hip/hip_bf16.h>

#define NBATCH 16
#define NBR    8
#define CIN    3
#define HIN    224
#define WIN    224
#define COUT   64
#define OHH    112
#define OWW    112
#define PHH    56
#define PWW    56
#define CNT    (NBATCH*OHH*OWW)                  // 200704 per (b,co) channel
#define YSLOT  ((size_t)NBATCH*OHH*OWW*COUT)     // y elements per branch

// padded x: per image [4 ci][230 h][232 w] bf16 (zeros baked in; ci=3 plane all-zero)
#define XCI  4
#define XH   230
#define XW   232
#define XIMG ((size_t)XCI*XH*XW)                 // 213440 elems per image
#define BROW 200                                 // Bt row stride in ushorts (192 + 8 pad)

typedef __bf16 bf16x8 __attribute__((ext_vector_type(8)));
typedef float  f32x4  __attribute__((ext_vector_type(4)));
typedef unsigned int uint4v __attribute__((ext_vector_type(4)));

// ---------- Bt[b][co][k'] bf16: k' = g*8+j, g=(ci*7+kh), j=kw (j=7 or g>=21 -> 0) ----------
__global__ __launch_bounds__(256)
void prep_w(const float* __restrict__ w, ushort* __restrict__ wt)
{
    int i = blockIdx.x*256 + threadIdx.x;
    if (i >= NBR*COUT*BROW) return;
    int k = i % BROW;
    int t = i / BROW;                       // b*64 + co
    float v = 0.f;
    if (k < 168) {
        int g = k >> 3, j = k & 7;
        if (j < 7) {
            int ci = g / 7, kh = g - 7*ci;
            v = w[(size_t)t*147 + ci*49 + kh*7 + j];
        }
    }
    __hip_bfloat16 h = __float2bfloat16(v);
    wt[i] = *reinterpret_cast<ushort*>(&h);
}

// ---------- padded bf16 x. interior only (memset provides zeros elsewhere) ----------
__global__ __launch_bounds__(256)
void prep_x(const float* __restrict__ x, ushort* __restrict__ xp)
{
    int bid = blockIdx.x;
    int hc  = bid % 14;
    int t2  = bid / 14;
    int ci  = t2 % 3;
    int img = t2 / 3;
    const float* src = x + ((size_t)img*3 + ci)*HIN*WIN;
    ushort* dst = xp + (size_t)img*XIMG + (size_t)ci*XH*XW;
    for (int i = threadIdx.x; i < 16*224; i += 256) {
        int hh = hc*16 + (i / 224);
        int c  = i % 224;
        float v = src[hh*WIN + c];
        __hip_bfloat16 h = __float2bfloat16(v);
        dst[(hh+3)*XW + (c+3)] = *reinterpret_cast<ushort*>(&h);
    }
}

// ---------- MFMA conv (unchanged from round 6) ----------
__global__ __launch_bounds__(256)
void conv_mfma(const ushort* __restrict__ xp, const ushort* __restrict__ wt,
               ushort* __restrict__ y, float* __restrict__ stats, int bbase)
{
    __shared__ ushort bt[COUT*BROW];     // 25600 B
    __shared__ float red[4][2][COUT];    // 2 KB

    int bloc = blockIdx.x / 224;
    int tb   = (blockIdx.x % 224) * 14;
    int b    = bbase + bloc;
    int tid  = threadIdx.x;
    int wid  = tid >> 6;
    int lane = tid & 63;
    int l15  = lane & 15;
    int q    = lane >> 4;

    {   // stage Bt into LDS
        const uint* s = (const uint*)(wt + (size_t)b*COUT*BROW);
        uint* d = (uint*)bt;
        for (int i = tid; i < COUT*BROW/2; i += 256) d[i] = s[i];
    }
    __syncthreads();

    uint4v bfr[4][6];
    #pragma unroll
    for (int nt = 0; nt < 4; ++nt)
        #pragma unroll
        for (int ks = 0; ks < 6; ++ks)
            bfr[nt][ks] = *(const uint4v*)&bt[(nt*16 + l15)*BROW + ks*32 + q*8];

    int goff[6];
    #pragma unroll
    for (int ks = 0; ks < 6; ++ks) {
        int g = ks*4 + q;
        int ci = g / 7, kh = g - 7*ci;
        goff[ks] = (ci*XH + kh) * (XW*2);
    }

    float ssum[4] = {0.f,0.f,0.f,0.f}, ssq[4] = {0.f,0.f,0.f,0.f};
    ushort* ybb = y + (size_t)bloc*YSLOT;

    for (int t = 0; t < 14; ++t) {
        int pxb = (tb + t)*64 + wid*16;
        int p   = pxb + l15;
        int n   = p / (OHH*OWW);
        int r1  = p - n*(OHH*OWW);
        int oh  = r1 / OWW;
        int ow  = r1 - oh*OWW;
        int img = n*NBR + b;
        const char* abase = (const char*)xp + (size_t)img*(XIMG*2)
                          + (size_t)(2*oh)*(XW*2) + (size_t)(4*ow);

        uint4v afr[6];
        #pragma unroll
        for (int ks = 0; ks < 6; ++ks)
            __builtin_memcpy(&afr[ks], abase + goff[ks], 16);

        f32x4 acc[4];
        #pragma unroll
        for (int nt = 0; nt < 4; ++nt) acc[nt] = (f32x4){0.f,0.f,0.f,0.f};

        #pragma unroll
        for (int ks = 0; ks < 6; ++ks)
            #pragma unroll
            for (int nt = 0; nt < 4; ++nt)
                acc[nt] = __builtin_amdgcn_mfma_f32_16x16x32_bf16(
                    __builtin_bit_cast(bf16x8, afr[ks]),
                    __builtin_bit_cast(bf16x8, bfr[nt][ks]),
                    acc[nt], 0, 0, 0);

        #pragma unroll
        for (int nt = 0; nt < 4; ++nt) {
            #pragma unroll
            for (int r = 0; r < 4; ++r) {
                float v = acc[nt][r];
                ssum[nt] += v; ssq[nt] += v*v;
                __hip_bfloat16 hv = __float2bfloat16(v);
                ybb[(size_t)(pxb + q*4 + r)*64 + nt*16 + l15] =
                    *reinterpret_cast<ushort*>(&hv);
            }
        }
    }

    #pragma unroll
    for (int nt = 0; nt < 4; ++nt) {
        float s = ssum[nt], qq = ssq[nt];
        s  += __shfl_xor(s, 16);  s  += __shfl_xor(s, 32);
        qq += __shfl_xor(qq, 16); qq += __shfl_xor(qq, 32);
        ssum[nt] = s; ssq[nt] = qq;
    }
    if (q == 0) {
        #pragma unroll
        for (int nt = 0; nt < 4; ++nt) {
            red[wid][0][nt*16 + l15] = ssum[nt];
            red[wid][1][nt*16 + l15] = ssq[nt];
        }
    }
    __syncthreads();
    if (tid < 64) {
        float s  = red[0][0][tid] + red[1][0][tid] + red[2][0][tid] + red[3][0][tid];
        float qq = red[0][1][tid] + red[1][1][tid] + red[2][1][tid] + red[3][1][tid];
        atomicAdd(&stats[b*128 + tid*2 + 0], s);
        atomicAdd(&stats[b*128 + tid*2 + 1], qq);
    }
}

// ---------- vectorized pool: uint4 reads (8 co / 16 B / lane), clamped windows ----------
__device__ __forceinline__ void upd8(const ushort* __restrict__ p,
                                     float* __restrict__ mx, float* __restrict__ mn)
{
    uint4v v = *(const uint4v*)p;
    #pragma unroll
    for (int i = 0; i < 4; ++i) {
        uint u = v[i];
        float f0 = __builtin_bit_cast(float, u << 16);
        float f1 = __builtin_bit_cast(float, u & 0xffff0000u);
        mx[2*i]   = fmaxf(mx[2*i],   f0);  mn[2*i]   = fminf(mn[2*i],   f0);
        mx[2*i+1] = fmaxf(mx[2*i+1], f1);  mn[2*i+1] = fminf(mn[2*i+1], f1);
    }
}

// block = one (bloc,n,ph) output row; thread = (pw-group, co-octet).
__global__ __launch_bounds__(256)
void pool_fast(const ushort* __restrict__ y, const float* __restrict__ stats,
               const float* __restrict__ gamma, const float* __restrict__ beta,
               float* __restrict__ out, int bbase)
{
    int bid  = blockIdx.x;
    int bloc = bid / (NBATCH*PHH);
    int r    = bid % (NBATCH*PHH);
    int n    = r / PHH;
    int ph   = r % PHH;
    int b    = bbase + bloc;
    int tid  = threadIdx.x;

    __shared__ float res[PWW][COUT+1];       // 14.6 KB
    __shared__ float sscale[COUT], sshift[COUT];

    if (tid < COUT) {
        float mean = stats[b*128 + tid*2 + 0] * (1.f/CNT);
        float var  = stats[b*128 + tid*2 + 1] * (1.f/CNT) - mean*mean;
        float inv  = rsqrtf(var + 1e-5f);
        float sc   = gamma[b*COUT + tid]*inv;
        sscale[tid] = sc;
        sshift[tid] = beta[b*COUT + tid] - mean*sc;
    }
    __syncthreads();

    const ushort* yb = y + (size_t)bloc*YSLOT + (size_t)n*OHH*OWW*64;
    int c8 = (tid & 7) * 8;      // co octet base
    int pg = tid >> 3;           // 0..31

    int ihA = (2*ph-1 < 0) ? 0 : 2*ph-1;
    int ihB = 2*ph;
    int ihC = (2*ph+1 > OHH-1) ? OHH-1 : 2*ph+1;
    const ushort* rA = yb + (size_t)ihA*OWW*64;
    const ushort* rB = yb + (size_t)ihB*OWW*64;
    const ushort* rC = yb + (size_t)ihC*OWW*64;

    #pragma unroll
    for (int t = 0; t < 2; ++t) {
        int pw = pg + 32*t;
        if (pw < PWW) {
            int iwL = (2*pw-1 < 0) ? 0 : 2*pw-1;
            int iwC = 2*pw;
            int iwR = (2*pw+1 > OWW-1) ? OWW-1 : 2*pw+1;
            int oL = iwL*64 + c8, oC = iwC*64 + c8, oR = iwR*64 + c8;

            float mx[8], mn[8];
            #pragma unroll
            for (int j = 0; j < 8; ++j) { mx[j] = -1e30f; mn[j] = 1e30f; }
            upd8(rA + oL, mx, mn); upd8(rA + oC, mx, mn); upd8(rA + oR, mx, mn);
            upd8(rB + oL, mx, mn); upd8(rB + oC, mx, mn); upd8(rB + oR, mx, mn);
            upd8(rC + oL, mx, mn); upd8(rC + oC, mx, mn); upd8(rC + oR, mx, mn);

            #pragma unroll
            for (int j = 0; j < 8; ++j) {
                int co = c8 + j;
                float sc = sscale[co];
                float v  = (sc >= 0.f) ? mx[j] : mn[j];   // affine+relu monotone
                res[pw][co] = fmaxf(fmaf(v, sc, sshift[co]), 0.f);
            }
        }
    }
    __syncthreads();

    float* ob = out + (((size_t)n*NBR + b)*COUT)*(PHH*PWW) + (size_t)ph*PWW;
    for (int j = tid; j < COUT*PWW; j += 256) {
        int co = j / PWW;
        int pw = j - co*PWW;
        ob[(size_t)co*(PHH*PWW) + pw] = res[pw][co];
    }
}

// ================= fallback path (tiny workspace) =================
__global__ __launch_bounds__(512)
void conv_bn_stats(const float* __restrict__ x, const float* __restrict__ w,
                   float* __restrict__ stats, int b)
{
    __shared__ float xs[CIN][7][232];
    int bid = blockIdx.x;
    int oh  = bid % OHH;
    int n   = bid / OHH;
    const float* xb = x + ((size_t)(n*NBR + b))*CIN*HIN*WIN;
    int ihb = oh*2 - 3;
    for (int idx = threadIdx.x; idx < CIN*7*230; idx += 512) {
        int ci = idx / (7*230);
        int rr = idx - ci*(7*230);
        int kh = rr / 230;
        int c  = rr - kh*230;
        int ih = ihb + kh, iw = c - 3;
        float v = 0.f;
        if ((unsigned)ih < (unsigned)HIN && (unsigned)iw < (unsigned)WIN)
            v = xb[(ci*HIN + ih)*WIN + iw];
        xs[ci][kh][c] = v;
    }
    __syncthreads();
    int wid  = __builtin_amdgcn_readfirstlane(threadIdx.x >> 6);
    int lane = threadIdx.x & 63;
    int co0  = wid * 8;
    const float* wb = w + ((size_t)b*COUT + co0)*147;
    float acc0[8], acc1[8];
    #pragma unroll
    for (int cc = 0; cc < 8; ++cc) { acc0[cc] = 0.f; acc1[cc] = 0.f; }
    int ow1 = lane + 64;
    for (int ci = 0; ci < CIN; ++ci)
        for (int kh = 0; kh < 7; ++kh) {
            float wr[8][7];
            #pragma unroll
            for (int cc = 0; cc < 8; ++cc)
                #pragma unroll
                for (int kw = 0; kw < 7; ++kw)
                    wr[cc][kw] = wb[cc*147 + ci*49 + kh*7 + kw];
            const float* xr = &xs[ci][kh][0];
            #pragma unroll
            for (int kw = 0; kw < 7; ++kw) {
                float xv0 = xr[lane*2 + kw];
                float xv1 = (ow1 < OWW) ? xr[ow1*2 + kw] : 0.f;
                #pragma unroll
                for (int cc = 0; cc < 8; ++cc) {
                    acc0[cc] = fmaf(xv0, wr[cc][kw], acc0[cc]);
                    acc1[cc] = fmaf(xv1, wr[cc][kw], acc1[cc]);
                }
            }
        }
    #pragma unroll
    for (int cc = 0; cc < 8; ++cc) {
        float s = acc0[cc] + acc1[cc];
        float qv = acc0[cc]*acc0[cc] + acc1[cc]*acc1[cc];
        #pragma unroll
        for (int off = 32; off; off >>= 1) {
            s  += __shfl_xor(s, off);
            qv += __shfl_xor(qv, off);
        }
        if (lane == 0) {
            atomicAdd(&stats[(co0+cc)*2 + 0], s);
            atomicAdd(&stats[(co0+cc)*2 + 1], qv);
        }
    }
}

__global__ __launch_bounds__(256)
void pool_recompute(const float* __restrict__ x, const float* __restrict__ w,
                    const float* __restrict__ stats, const float* __restrict__ gamma,
                    const float* __restrict__ beta, float* __restrict__ out, int b)
{
    int idx = blockIdx.x*256 + threadIdx.x;
    int pw = idx % PWW;
    int t  = idx / PWW;
    int ph = t % PHH; t /= PHH;
    int co = t % COUT;
    int n  = t / COUT;
    float mean = stats[co*2 + 0] * (1.f/CNT);
    float var  = stats[co*2 + 1] * (1.f/CNT) - mean*mean;
    float inv  = rsqrtf(var + 1e-5f);
    float scale = gamma[co]*inv;
    float shift = beta[co] - mean*scale;
    const float* xb = x + ((size_t)(n*NBR + b))*CIN*HIN*WIN;
    const float* wb = w + ((size_t)b*COUT + co)*147;
    float mx = -1e30f, mn = 1e30f;
    for (int dh = 0; dh < 3; ++dh) {
        int oh = 2*ph - 1 + dh;
        if ((unsigned)oh >= (unsigned)OHH) continue;
        for (int dw = 0; dw < 3; ++dw) {
            int ow = 2*pw - 1 + dw;
            if ((unsigned)ow >= (unsigned)OWW) continue;
            float a = 0.f;
            for (int ci = 0; ci < CIN; ++ci)
                for (int kh = 0; kh < 7; ++kh) {
                    int ih = oh*2 - 3 + kh;
                    if ((unsigned)ih >= (unsigned)HIN) continue;
                    for (int kw = 0; kw < 7; ++kw) {
                        int iw = ow*2 - 3 + kw;
                        if ((unsigned)iw >= (unsigned)WIN) continue;
                        a = fmaf(xb[(ci*HIN + ih)*WIN + iw], wb[ci*49 + kh*7 + kw], a);
                    }
                }
            mx = fmaxf(mx, a);
            mn = fminf(mn, a);
        }
    }
    float v = (scale >= 0.f) ? mx : mn;
    out[(((size_t)n*NBR + b)*COUT + co)*(PHH*PWW) + (size_t)ph*PWW + pw] =
        fmaxf(fmaf(v, scale, shift), 0.f);
}

extern "C" void kernel_launch(void* const* d_in, const int* in_sizes, int n_in,
                              void* d_out, int out_size, void* d_ws, size_t ws_size,
                              hipStream_t stream) {
    const float* x     = (const float*)d_in[0];
    const float* w     = (const float*)d_in[1];
    const float* gamma = (const float*)d_in[2];
    const float* beta  = (const float*)d_in[3];
    float* out = (float*)d_out;

    // ws: [0,4K) stats; [4K,~209K) wt (8x64x200 bf16); [256K, +54.6MB) xpad; then y slots
    float*  stats = (float*)d_ws;
    ushort* wt    = (ushort*)((char*)d_ws + 4096);
    ushort* xp    = (ushort*)((char*)d_ws + 262144);
    const size_t ybase  = 262144 + (size_t)128*XIMG*2;   // ~54.9 MB
    const size_t yBytes = YSLOT*2;                       // 25.69 MB per branch
    ushort* y = (ushort*)((char*)d_ws + ybase);

    int ng = 0;
    if (ws_size > ybase + yBytes)
        ng = (int)((ws_size - ybase) / yBytes);
    if (ng > NBR) ng = NBR;

    if (ng >= 1) {
        hipMemsetAsync(d_ws, 0, ybase, stream);   // zeros stats + wt pad + xpad padding
        prep_w<<<(NBR*COUT*BROW + 255)/256, 256, 0, stream>>>(w, wt);
        prep_x<<<128*3*14, 256, 0, stream>>>(x, xp);
        for (int g = 0; g < NBR; g += ng) {
            int nb = (NBR - g < ng) ? (NBR - g) : ng;
            conv_mfma<<<nb*224, 256, 0, stream>>>(xp, wt, y, stats, g);
            pool_fast<<<nb*NBATCH*PHH, 256, 0, stream>>>(y, stats, gamma, beta, out, g);
        }
    } else {
        hipMemsetAsync(d_ws, 0, NBR*128*sizeof(float), stream);
        for (int b = 0; b < NBR; ++b) {
            float* statsB = stats + b*128;
            conv_bn_stats<<<NBATCH*OHH, 512, 0, stream>>>(x, w, statsB, b);
            pool_recompute<<<NBATCH*COUT*PHH*PWW/256, 256, 0, stream>>>(
                x, w, statsB, gamma + b*COUT, beta + b*COUT, out, b);
        }
    }
}